// Round 9
// baseline (4632.986 us; speedup 1.0000x reference)
//
#include <hip/hip_runtime.h>

#define SPATIAL 32768
#define BATCH   4
#define CH      256
#define KCODES  1024
#define NPTS    (BATCH*SPATIAL)          // 131072
#define ZQ_SIZE (BATCH*CH*SPATIAL)       // 33554432

// workspace layout (bytes)
#define WS_LOSS  0                        // double
#define WS_CNT   8                        // int
#define WS_ENORM 16                       // float[1024]
#define WS_EH    4352                     // _Float16[1024*256] row-major
#define WS_EL    (WS_EH + KCODES*CH*2)
#define WS_FLAGS (WS_EL + KCODES*CH*2)    // int[NPTS]

#define MARG 1.5e-4f  // covers split err + MFMA-vs-chain diff + 2 ulp(512)

typedef _Float16 f16x8 __attribute__((ext_vector_type(8)));
typedef float    f32x4 __attribute__((ext_vector_type(4)));

// split e*1024 into f16 hi/lo, row-major
__global__ __launch_bounds__(256) void vq_prep(const float* __restrict__ emb,
                                               _Float16* __restrict__ eh,
                                               _Float16* __restrict__ el) {
  int i = blockIdx.x * 256 + threadIdx.x;
  float es = emb[i] * 1024.0f;
  _Float16 h = (_Float16)es;
  eh[i] = h;
  el[i] = (_Float16)(es - (float)h);
}

__global__ __launch_bounds__(256) void vq_enorm(const float* __restrict__ emb,
                                                float* __restrict__ enorm) {
  int k = blockIdx.x * 256 + threadIdx.x;
  const float* e = emb + (size_t)k * CH;
  double s = 0.0;
#pragma unroll 8
  for (int c = 0; c < CH; ++c) s = fma((double)e[c], (double)e[c], s);
  enorm[k] = (float)s;
}

// 2048 blocks x 256 thr; block = 64 points x all 1024 codes, f16-split MFMA.
// m=4,n=2 per wave (24 MFMA per 4 B-loads); close-bitmask replaces rm2;
// scatter fused at the end reusing zfrag LDS as the f32 row buffer.
__global__ __launch_bounds__(256) void vq_main(
    const float* __restrict__ z, const _Float16* __restrict__ eh_g,
    const _Float16* __restrict__ el_g, const float* __restrict__ enorm,
    const float* __restrict__ emb, float* __restrict__ out_idx,
    float* __restrict__ zq, double* __restrict__ loss_acc,
    int* __restrict__ flag_cnt, int* __restrict__ flags) {
  __shared__ __align__(16) char smem[65536];
  f16x8 (*zfrag)[64] = reinterpret_cast<f16x8(*)[64]>(smem);  // 64 KB
  float (*rows)[256] = reinterpret_cast<float(*)[256]>(smem); // union, post-K
  __shared__ double znp[4][64];
  __shared__ float  znb[64];
  __shared__ float rm1s[4][64];
  __shared__ int   ri1s[4][64];
  __shared__ int   closs[4][64];
  __shared__ int   idx_sh[64];

  int tid = threadIdx.x;
  int w = tid >> 6;
  int lane = tid & 63;
  int n0 = blockIdx.x * 64;
  int b = n0 / SPATIAL, s0 = n0 % SPATIAL;
  const float* zb = z + (size_t)b * CH * SPATIAL + s0;

  // stage z as f16 hi/lo in fragment order; f64 zn partials
  {
    int pt = lane, m = pt >> 4, lr0 = pt & 15;
    const float* zcol = zb + pt;
    double zacc = 0.0;
#pragma unroll
    for (int oct = 0; oct < 8; ++oct) {
      int c0 = w * 64 + oct * 8;
      int cc = c0 >> 5, hq0 = (c0 >> 3) & 3;
      f16x8 h8, l8;
#pragma unroll
      for (int i = 0; i < 8; ++i) {
        float v = zcol[(size_t)(c0 + i) * SPATIAL];
        zacc = fma((double)v, (double)v, zacc);
        _Float16 hh = (_Float16)v;
        h8[i] = hh;
        l8[i] = (_Float16)(v - (float)hh);
      }
      zfrag[m * 8 + cc][hq0 * 16 + lr0] = h8;
      zfrag[32 + m * 8 + cc][hq0 * 16 + lr0] = l8;
    }
    znp[w][pt] = zacc;
  }
  __syncthreads();
  if (tid < 64)
    znb[tid] = (float)(znp[0][tid] + znp[1][tid] + znp[2][tid] + znp[3][tid]);
  __syncthreads();

  int hq = lane >> 4;
  int lr = lane & 15;

  float znr[16];
#pragma unroll
  for (int m = 0; m < 4; ++m)
#pragma unroll
    for (int r = 0; r < 4; ++r) znr[m * 4 + r] = znb[m * 16 + hq * 4 + r];

  float rm1[16];
  int   ri1[16];
  int   close = 0;
#pragma unroll
  for (int q = 0; q < 16; ++q) { rm1[q] = 1e30f; ri1[q] = 0; }

  const _Float16* ehb = eh_g + (size_t)(w * 32 + lr) * CH;
  const _Float16* elb = el_g + (size_t)(w * 32 + lr) * CH;

  for (int kt = 0; kt < 8; ++kt) {
    size_t ko = (size_t)kt * 128 * CH;
    f32x4 acc[4][2];
#pragma unroll
    for (int m = 0; m < 4; ++m)
#pragma unroll
      for (int n = 0; n < 2; ++n) acc[m][n] = (f32x4){0.f, 0.f, 0.f, 0.f};

#pragma unroll
    for (int cc = 0; cc < 8; ++cc) {
      int ca = cc * 32 + hq * 8;
      f16x8 bh0 = *(const f16x8*)&ehb[ko + ca];
      f16x8 bh1 = *(const f16x8*)&ehb[ko + (size_t)16 * CH + ca];
      f16x8 bl0 = *(const f16x8*)&elb[ko + ca];
      f16x8 bl1 = *(const f16x8*)&elb[ko + (size_t)16 * CH + ca];
#pragma unroll
      for (int m = 0; m < 4; ++m) {
        f16x8 ah = zfrag[m * 8 + cc][lane];
        f16x8 al = zfrag[32 + m * 8 + cc][lane];
        acc[m][0] = __builtin_amdgcn_mfma_f32_16x16x32_f16(ah, bh0, acc[m][0], 0, 0, 0);
        acc[m][0] = __builtin_amdgcn_mfma_f32_16x16x32_f16(al, bh0, acc[m][0], 0, 0, 0);
        acc[m][0] = __builtin_amdgcn_mfma_f32_16x16x32_f16(ah, bl0, acc[m][0], 0, 0, 0);
        acc[m][1] = __builtin_amdgcn_mfma_f32_16x16x32_f16(ah, bh1, acc[m][1], 0, 0, 0);
        acc[m][1] = __builtin_amdgcn_mfma_f32_16x16x32_f16(al, bh1, acc[m][1], 0, 0, 0);
        acc[m][1] = __builtin_amdgcn_mfma_f32_16x16x32_f16(ah, bl1, acc[m][1], 0, 0, 0);
      }
    }

    // fold (D-frag: row = hq*4+r, col = lr); close-bit: |p - running_m1|<=MARG
    float enA = enorm[kt * 128 + w * 32 + lr];
    float enB = enorm[kt * 128 + w * 32 + 16 + lr];
    int c0i = kt * 128 + w * 32 + lr;
#pragma unroll
    for (int m = 0; m < 4; ++m) {
#pragma unroll
      for (int r = 0; r < 4; ++r) {
        int q = m * 4 + r;
        float zn = znr[q];
        float t0 = zn + enA;
        float p0 = fmaf(acc[m][0][r], -0x1p-9f, t0);
        close |= (fabsf(p0 - rm1[q]) <= MARG) ? (1 << q) : 0;
        if (p0 < rm1[q]) { rm1[q] = p0; ri1[q] = c0i; }
        float t1 = zn + enB;
        float p1 = fmaf(acc[m][1][r], -0x1p-9f, t1);
        close |= (fabsf(p1 - rm1[q]) <= MARG) ? (1 << q) : 0;
        if (p1 < rm1[q]) { rm1[q] = p1; ri1[q] = c0i + 16; }
      }
    }
  }

  // one butterfly across the 16 lr-lanes (close mask shuffled once per step)
#pragma unroll
  for (int msk = 1; msk <= 8; msk <<= 1) {
    int nclose = close | __shfl_xor(close, msk);
#pragma unroll
    for (int q = 0; q < 16; ++q) {
      float om1 = __shfl_xor(rm1[q], msk);
      int   oi1 = __shfl_xor(ri1[q], msk);
      nclose |= (fabsf(rm1[q] - om1) <= MARG) ? (1 << q) : 0;
      if (om1 < rm1[q] || (om1 == rm1[q] && oi1 < ri1[q])) {
        rm1[q] = om1; ri1[q] = oi1;
      }
    }
    close = nclose;
  }
  if (lr == 0) {
#pragma unroll
    for (int m = 0; m < 4; ++m)
#pragma unroll
      for (int r = 0; r < 4; ++r) {
        int q = m * 4 + r;
        int pt = m * 16 + hq * 4 + r;
        rm1s[w][pt] = rm1[q]; ri1s[w][pt] = ri1[q];
        closs[w][pt] = (close >> q) & 1;
      }
  }
  __syncthreads();

  if (tid < 64) {
    float m1 = rm1s[0][tid];
    int i1 = ri1s[0][tid];
    int cl = closs[0][tid];
#pragma unroll
    for (int pq = 1; pq < 4; ++pq) {
      float a1 = rm1s[pq][tid];
      int ai = ri1s[pq][tid];
      cl |= closs[pq][tid] | ((fabsf(m1 - a1) <= MARG) ? 1 : 0);
      if (a1 < m1 || (a1 == m1 && ai < i1)) { m1 = a1; i1 = ai; }
    }
    int n = n0 + tid;
    out_idx[n] = (float)i1;
    idx_sh[tid] = i1;
    if (cl) {
      int p = atomicAdd(flag_cnt, 1);
      if (p < NPTS) flags[p] = n;
    }
    double dv = (double)m1;
#pragma unroll
    for (int msk = 1; msk < 64; msk <<= 1) dv += __shfl_xor(dv, msk);
    if (tid == 0) atomicAdd(loss_acc, dv);
  }
  __syncthreads();

  // fused scatter: gather emb rows once into XOR-swizzled LDS (zfrag space),
  // write z_q transposed coalesced
  for (int r = w; r < 64; r += 4) {
    const float* er = emb + (size_t)idx_sh[r] * CH;
    int sw = r & 31;
#pragma unroll
    for (int i = 0; i < 4; ++i) {
      int c = lane + 64 * i;
      rows[r][c ^ sw] = er[c];
    }
  }
  __syncthreads();
  for (int it = 0; it < 64; ++it) {
    int c = w * 64 + it;
    float v = rows[lane][c ^ (lane & 31)];
    zq[((size_t)(b * CH + c)) * SPATIAL + s0 + lane] = v;
  }
}

// exact numpy-fp32-chain re-decision for flagged points; repairs z_q rows
// whose index changed; finalizes loss.
__global__ __launch_bounds__(256) void vq_recheck(
    const float* __restrict__ z, const float* __restrict__ emb,
    const float* __restrict__ enorm, const int* __restrict__ flag_cnt,
    const int* __restrict__ flags, float* __restrict__ out_idx,
    float* __restrict__ zq, const double* __restrict__ loss_acc,
    float* __restrict__ loss_out) {
  if (blockIdx.x == 0 && threadIdx.x == 0)
    loss_out[0] = (float)(loss_acc[0] * 1.25 / (double)ZQ_SIZE);
  __shared__ float zs[4][CH];
  __shared__ float znf[4];
  __shared__ float bm[256];
  __shared__ int   bi[256];
  __shared__ int   s_n[4], s_old[4], s_new[4];
  int cnt = *flag_cnt; if (cnt > NPTS) cnt = NPTS;
  int t = threadIdx.x;
  for (int base = blockIdx.x * 4; base < cnt; base += gridDim.x * 4) {
    if (t < 4) {
      int ii = base + t; if (ii >= cnt) ii = cnt - 1;
      int nn = flags[ii];
      s_n[t] = nn;
      s_old[t] = (int)out_idx[nn];
    }
    __syncthreads();
#pragma unroll
    for (int q = 0; q < 4; ++q) {
      int n = s_n[q];
      int b = n / SPATIAL, s = n % SPATIAL;
      zs[q][t] = z[((size_t)b * CH + t) * SPATIAL + s];
    }
    __syncthreads();
    if (t < 4) {
      double sd = 0.0;
      for (int c = 0; c < CH; ++c) sd = fma((double)zs[t][c], (double)zs[t][c], sd);
      znf[t] = (float)sd;
    }
    __syncthreads();
    float best[4] = {1e30f, 1e30f, 1e30f, 1e30f};
    int besti[4] = {0, 0, 0, 0};
    for (int q = 0; q < 4; ++q) {
      int code = t + 256 * q;
      const float* er = emb + (size_t)code * CH;
      float g0 = 0.f, g1 = 0.f, g2 = 0.f, g3 = 0.f;
#pragma unroll 8
      for (int c = 0; c < CH; ++c) {
        float e = er[c];
        g0 = fmaf(zs[0][c], e, g0);
        g1 = fmaf(zs[1][c], e, g1);
        g2 = fmaf(zs[2][c], e, g2);
        g3 = fmaf(zs[3][c], e, g3);
      }
      float en = enorm[code];
      float d0 = (znf[0] + en) - 2.f * g0;
      float d1 = (znf[1] + en) - 2.f * g1;
      float d2 = (znf[2] + en) - 2.f * g2;
      float d3 = (znf[3] + en) - 2.f * g3;
      if (d0 < best[0]) { best[0] = d0; besti[0] = code; }
      if (d1 < best[1]) { best[1] = d1; besti[1] = code; }
      if (d2 < best[2]) { best[2] = d2; besti[2] = code; }
      if (d3 < best[3]) { best[3] = d3; besti[3] = code; }
    }
#pragma unroll
    for (int p = 0; p < 4; ++p) {
      bm[t] = best[p]; bi[t] = besti[p];
      __syncthreads();
      for (int off = 128; off > 0; off >>= 1) {
        if (t < off) {
          float ob = bm[t + off]; int oi = bi[t + off];
          if (ob < bm[t] || (ob == bm[t] && oi < bi[t])) { bm[t] = ob; bi[t] = oi; }
        }
        __syncthreads();
      }
      int ii = base + p;
      if (t == 0) {
        s_new[p] = bi[0];
        if (ii < cnt) out_idx[flags[ii]] = (float)bi[0];
      }
      __syncthreads();
    }
    // repair z_q rows whose index changed (thread t = channel t)
#pragma unroll
    for (int p = 0; p < 4; ++p) {
      int ii = base + p;
      if (ii < cnt && s_new[p] != s_old[p]) {
        int n = s_n[p];
        int b = n / SPATIAL, s = n % SPATIAL;
        zq[((size_t)(b * CH + t)) * SPATIAL + s] = emb[(size_t)s_new[p] * CH + t];
      }
    }
    __syncthreads();
  }
}

extern "C" void kernel_launch(void* const* d_in, const int* in_sizes, int n_in,
                              void* d_out, int out_size, void* d_ws, size_t ws_size,
                              hipStream_t stream) {
  const float* z   = (const float*)d_in[0];
  const float* emb = (const float*)d_in[1];
  float* out = (float*)d_out;
  char* ws = (char*)d_ws;

  double*   loss_acc = (double*)(ws + WS_LOSS);
  int*      flag_cnt = (int*)(ws + WS_CNT);
  float*    enorm    = (float*)(ws + WS_ENORM);
  _Float16* eh       = (_Float16*)(ws + WS_EH);
  _Float16* el       = (_Float16*)(ws + WS_EL);
  int*      flags    = (int*)(ws + WS_FLAGS);

  float* loss_out = out + ZQ_SIZE;
  float* out_idx  = out + ZQ_SIZE + 1;

  hipMemsetAsync(d_ws, 0, 16, stream);
  vq_prep<<<KCODES * CH / 256, 256, 0, stream>>>(emb, eh, el);
  vq_enorm<<<KCODES / 256, 256, 0, stream>>>(emb, enorm);
  vq_main<<<NPTS / 64, 256, 0, stream>>>(z, eh, el, enorm, emb, out_idx, out,
                                         loss_acc, flag_cnt, flags);
  vq_recheck<<<512, 256, 0, stream>>>(z, emb, enorm, flag_cnt, flags, out_idx,
                                      out, loss_acc, loss_out);
}

// Round 10
// 808.256 us; speedup vs baseline: 5.7321x; 5.7321x over previous
//
#include <hip/hip_runtime.h>

#define SPATIAL 32768
#define BATCH   4
#define CH      256
#define KCODES  1024
#define NPTS    (BATCH*SPATIAL)          // 131072
#define ZQ_SIZE (BATCH*CH*SPATIAL)       // 33554432

// workspace layout (bytes)
#define WS_LOSS  0                        // double
#define WS_CNT   8                        // int
#define WS_ENORM 16                       // float[1024]
#define WS_EH    4352                     // _Float16[1024*256] row-major
#define WS_EL    (WS_EH + KCODES*CH*2)
#define WS_FLAGS (WS_EL + KCODES*CH*2)    // int[NPTS]

#define MARG 1.5e-4f  // covers split err + MFMA-vs-chain diff + 2 ulp(512)

typedef _Float16 f16x8 __attribute__((ext_vector_type(8)));
typedef float    f32x4 __attribute__((ext_vector_type(4)));

// split e*1024 into f16 hi/lo, row-major
__global__ __launch_bounds__(256) void vq_prep(const float* __restrict__ emb,
                                               _Float16* __restrict__ eh,
                                               _Float16* __restrict__ el) {
  int i = blockIdx.x * 256 + threadIdx.x;
  float es = emb[i] * 1024.0f;
  _Float16 h = (_Float16)es;
  eh[i] = h;
  el[i] = (_Float16)(es - (float)h);
}

__global__ __launch_bounds__(256) void vq_enorm(const float* __restrict__ emb,
                                                float* __restrict__ enorm) {
  int k = blockIdx.x * 256 + threadIdx.x;
  const float* e = emb + (size_t)k * CH;
  double s = 0.0;
#pragma unroll 8
  for (int c = 0; c < CH; ++c) s = fma((double)e[c], (double)e[c], s);
  enorm[k] = (float)s;
}

// 2048 blocks x 256 thr; block = 64 points x all 1024 codes, f16-split MFMA.
// m=4,n=2 per wave; exact per-thread top-2 (flag iff final m2-m1<=MARG);
// scatter fused at the end reusing zfrag LDS as the f32 row buffer.
__global__ __launch_bounds__(256) void vq_main(
    const float* __restrict__ z, const _Float16* __restrict__ eh_g,
    const _Float16* __restrict__ el_g, const float* __restrict__ enorm,
    const float* __restrict__ emb, float* __restrict__ out_idx,
    float* __restrict__ zq, double* __restrict__ loss_acc,
    int* __restrict__ flag_cnt, int* __restrict__ flags) {
  __shared__ __align__(16) char smem[65536];
  f16x8 (*zfrag)[64] = reinterpret_cast<f16x8(*)[64]>(smem);  // 64 KB
  float (*rows)[256] = reinterpret_cast<float(*)[256]>(smem); // union, post-K
  __shared__ double znp[4][64];
  __shared__ float  znb[64];
  __shared__ float rm1s[4][64];
  __shared__ float rm2s[4][64];
  __shared__ int   ri1s[4][64];
  __shared__ int   idx_sh[64];

  int tid = threadIdx.x;
  int w = tid >> 6;
  int lane = tid & 63;
  int n0 = blockIdx.x * 64;
  int b = n0 / SPATIAL, s0 = n0 % SPATIAL;
  const float* zb = z + (size_t)b * CH * SPATIAL + s0;

  // stage z as f16 hi/lo in fragment order; f64 zn partials
  {
    int pt = lane, m = pt >> 4, lr0 = pt & 15;
    const float* zcol = zb + pt;
    double zacc = 0.0;
#pragma unroll
    for (int oct = 0; oct < 8; ++oct) {
      int c0 = w * 64 + oct * 8;
      int cc = c0 >> 5, hq0 = (c0 >> 3) & 3;
      f16x8 h8, l8;
#pragma unroll
      for (int i = 0; i < 8; ++i) {
        float v = zcol[(size_t)(c0 + i) * SPATIAL];
        zacc = fma((double)v, (double)v, zacc);
        _Float16 hh = (_Float16)v;
        h8[i] = hh;
        l8[i] = (_Float16)(v - (float)hh);
      }
      zfrag[m * 8 + cc][hq0 * 16 + lr0] = h8;
      zfrag[32 + m * 8 + cc][hq0 * 16 + lr0] = l8;
    }
    znp[w][pt] = zacc;
  }
  __syncthreads();
  if (tid < 64)
    znb[tid] = (float)(znp[0][tid] + znp[1][tid] + znp[2][tid] + znp[3][tid]);
  __syncthreads();

  int hq = lane >> 4;
  int lr = lane & 15;

  float znr[16];
#pragma unroll
  for (int m = 0; m < 4; ++m)
#pragma unroll
    for (int r = 0; r < 4; ++r) znr[m * 4 + r] = znb[m * 16 + hq * 4 + r];

  float rm1[16], rm2[16];
  int   ri1[16];
#pragma unroll
  for (int q = 0; q < 16; ++q) { rm1[q] = 1e30f; rm2[q] = 1e30f; ri1[q] = 0; }

  const _Float16* ehb = eh_g + (size_t)(w * 32 + lr) * CH;
  const _Float16* elb = el_g + (size_t)(w * 32 + lr) * CH;

  for (int kt = 0; kt < 8; ++kt) {
    size_t ko = (size_t)kt * 128 * CH;
    f32x4 acc[4][2];
#pragma unroll
    for (int m = 0; m < 4; ++m)
#pragma unroll
      for (int n = 0; n < 2; ++n) acc[m][n] = (f32x4){0.f, 0.f, 0.f, 0.f};

#pragma unroll
    for (int cc = 0; cc < 8; ++cc) {
      int ca = cc * 32 + hq * 8;
      f16x8 bh0 = *(const f16x8*)&ehb[ko + ca];
      f16x8 bh1 = *(const f16x8*)&ehb[ko + (size_t)16 * CH + ca];
      f16x8 bl0 = *(const f16x8*)&elb[ko + ca];
      f16x8 bl1 = *(const f16x8*)&elb[ko + (size_t)16 * CH + ca];
#pragma unroll
      for (int m = 0; m < 4; ++m) {
        f16x8 ah = zfrag[m * 8 + cc][lane];
        f16x8 al = zfrag[32 + m * 8 + cc][lane];
        acc[m][0] = __builtin_amdgcn_mfma_f32_16x16x32_f16(ah, bh0, acc[m][0], 0, 0, 0);
        acc[m][0] = __builtin_amdgcn_mfma_f32_16x16x32_f16(al, bh0, acc[m][0], 0, 0, 0);
        acc[m][0] = __builtin_amdgcn_mfma_f32_16x16x32_f16(ah, bl0, acc[m][0], 0, 0, 0);
        acc[m][1] = __builtin_amdgcn_mfma_f32_16x16x32_f16(ah, bh1, acc[m][1], 0, 0, 0);
        acc[m][1] = __builtin_amdgcn_mfma_f32_16x16x32_f16(al, bh1, acc[m][1], 0, 0, 0);
        acc[m][1] = __builtin_amdgcn_mfma_f32_16x16x32_f16(ah, bl1, acc[m][1], 0, 0, 0);
      }
    }

    // fold into per-thread top-2 (D-frag: row = hq*4+r, col = lr)
    float enA = enorm[kt * 128 + w * 32 + lr];
    float enB = enorm[kt * 128 + w * 32 + 16 + lr];
    int c0i = kt * 128 + w * 32 + lr;
#pragma unroll
    for (int m = 0; m < 4; ++m) {
#pragma unroll
      for (int r = 0; r < 4; ++r) {
        int q = m * 4 + r;
        float zn = znr[q];
        float p0 = fmaf(acc[m][0][r], -0x1p-9f, zn + enA);
        if (p0 < rm1[q]) { rm2[q] = rm1[q]; rm1[q] = p0; ri1[q] = c0i; }
        else             { rm2[q] = fminf(rm2[q], p0); }
        float p1 = fmaf(acc[m][1][r], -0x1p-9f, zn + enB);
        if (p1 < rm1[q]) { rm2[q] = rm1[q]; rm1[q] = p1; ri1[q] = c0i + 16; }
        else             { rm2[q] = fminf(rm2[q], p1); }
      }
    }
  }

  // one butterfly per row across the 16 lr-lanes (true top-2 merge)
#pragma unroll
  for (int m = 0; m < 4; ++m) {
#pragma unroll
    for (int r = 0; r < 4; ++r) {
      int q = m * 4 + r;
      float m1 = rm1[q], m2 = rm2[q];
      int i1 = ri1[q];
#pragma unroll
      for (int msk = 1; msk <= 8; msk <<= 1) {
        float om1 = __shfl_xor(m1, msk);
        float om2 = __shfl_xor(m2, msk);
        int   oi1 = __shfl_xor(i1, msk);
        if (om1 < m1 || (om1 == m1 && oi1 < i1)) {
          m2 = fminf(m1, om2); m1 = om1; i1 = oi1;
        } else {
          m2 = fminf(m2, om1);
        }
      }
      if (lr == 0) {
        int pt = m * 16 + hq * 4 + r;
        rm1s[w][pt] = m1; rm2s[w][pt] = m2; ri1s[w][pt] = i1;
      }
    }
  }
  __syncthreads();

  if (tid < 64) {
    float m1 = rm1s[0][tid], m2 = rm2s[0][tid];
    int i1 = ri1s[0][tid];
#pragma unroll
    for (int pq = 1; pq < 4; ++pq) {
      float a1 = rm1s[pq][tid], a2 = rm2s[pq][tid];
      int ai = ri1s[pq][tid];
      if (a1 < m1 || (a1 == m1 && ai < i1)) {
        m2 = fminf(m1, a2); m1 = a1; i1 = ai;
      } else {
        m2 = fminf(m2, a1);
      }
    }
    int n = n0 + tid;
    out_idx[n] = (float)i1;
    idx_sh[tid] = i1;
    if (m2 - m1 <= MARG) {
      int p = atomicAdd(flag_cnt, 1);
      if (p < NPTS) flags[p] = n;
    }
    double dv = (double)m1;
#pragma unroll
    for (int msk = 1; msk < 64; msk <<= 1) dv += __shfl_xor(dv, msk);
    if (tid == 0) atomicAdd(loss_acc, dv);
  }
  __syncthreads();

  // fused scatter: gather emb rows once into XOR-swizzled LDS (zfrag space),
  // write z_q transposed coalesced
  for (int r = w; r < 64; r += 4) {
    const float* er = emb + (size_t)idx_sh[r] * CH;
    int sw = r & 31;
#pragma unroll
    for (int i = 0; i < 4; ++i) {
      int c = lane + 64 * i;
      rows[r][c ^ sw] = er[c];
    }
  }
  __syncthreads();
  for (int it = 0; it < 64; ++it) {
    int c = w * 64 + it;
    float v = rows[lane][c ^ (lane & 31)];
    zq[((size_t)(b * CH + c)) * SPATIAL + s0 + lane] = v;
  }
}

// exact numpy-fp32-chain re-decision for flagged points; repairs z_q rows
// whose index changed; finalizes loss.
__global__ __launch_bounds__(256) void vq_recheck(
    const float* __restrict__ z, const float* __restrict__ emb,
    const float* __restrict__ enorm, const int* __restrict__ flag_cnt,
    const int* __restrict__ flags, float* __restrict__ out_idx,
    float* __restrict__ zq, const double* __restrict__ loss_acc,
    float* __restrict__ loss_out) {
  if (blockIdx.x == 0 && threadIdx.x == 0)
    loss_out[0] = (float)(loss_acc[0] * 1.25 / (double)ZQ_SIZE);
  __shared__ float zs[4][CH];
  __shared__ float znf[4];
  __shared__ float bm[256];
  __shared__ int   bi[256];
  __shared__ int   s_n[4], s_old[4], s_new[4];
  int cnt = *flag_cnt; if (cnt > NPTS) cnt = NPTS;
  int t = threadIdx.x;
  for (int base = blockIdx.x * 4; base < cnt; base += gridDim.x * 4) {
    if (t < 4) {
      int ii = base + t; if (ii >= cnt) ii = cnt - 1;
      int nn = flags[ii];
      s_n[t] = nn;
      s_old[t] = (int)out_idx[nn];
    }
    __syncthreads();
#pragma unroll
    for (int q = 0; q < 4; ++q) {
      int n = s_n[q];
      int b = n / SPATIAL, s = n % SPATIAL;
      zs[q][t] = z[((size_t)b * CH + t) * SPATIAL + s];
    }
    __syncthreads();
    if (t < 4) {
      double sd = 0.0;
      for (int c = 0; c < CH; ++c) sd = fma((double)zs[t][c], (double)zs[t][c], sd);
      znf[t] = (float)sd;
    }
    __syncthreads();
    float best[4] = {1e30f, 1e30f, 1e30f, 1e30f};
    int besti[4] = {0, 0, 0, 0};
    for (int q = 0; q < 4; ++q) {
      int code = t + 256 * q;
      const float* er = emb + (size_t)code * CH;
      float g0 = 0.f, g1 = 0.f, g2 = 0.f, g3 = 0.f;
#pragma unroll 8
      for (int c = 0; c < CH; ++c) {
        float e = er[c];
        g0 = fmaf(zs[0][c], e, g0);
        g1 = fmaf(zs[1][c], e, g1);
        g2 = fmaf(zs[2][c], e, g2);
        g3 = fmaf(zs[3][c], e, g3);
      }
      float en = enorm[code];
      float d0 = (znf[0] + en) - 2.f * g0;
      float d1 = (znf[1] + en) - 2.f * g1;
      float d2 = (znf[2] + en) - 2.f * g2;
      float d3 = (znf[3] + en) - 2.f * g3;
      if (d0 < best[0]) { best[0] = d0; besti[0] = code; }
      if (d1 < best[1]) { best[1] = d1; besti[1] = code; }
      if (d2 < best[2]) { best[2] = d2; besti[2] = code; }
      if (d3 < best[3]) { best[3] = d3; besti[3] = code; }
    }
#pragma unroll
    for (int p = 0; p < 4; ++p) {
      bm[t] = best[p]; bi[t] = besti[p];
      __syncthreads();
      for (int off = 128; off > 0; off >>= 1) {
        if (t < off) {
          float ob = bm[t + off]; int oi = bi[t + off];
          if (ob < bm[t] || (ob == bm[t] && oi < bi[t])) { bm[t] = ob; bi[t] = oi; }
        }
        __syncthreads();
      }
      int ii = base + p;
      if (t == 0) {
        s_new[p] = bi[0];
        if (ii < cnt) out_idx[flags[ii]] = (float)bi[0];
      }
      __syncthreads();
    }
    // repair z_q rows whose index changed (thread t = channel t)
#pragma unroll
    for (int p = 0; p < 4; ++p) {
      int ii = base + p;
      if (ii < cnt && s_new[p] != s_old[p]) {
        int n = s_n[p];
        int b = n / SPATIAL, s = n % SPATIAL;
        zq[((size_t)(b * CH + t)) * SPATIAL + s] = emb[(size_t)s_new[p] * CH + t];
      }
    }
    __syncthreads();
  }
}

extern "C" void kernel_launch(void* const* d_in, const int* in_sizes, int n_in,
                              void* d_out, int out_size, void* d_ws, size_t ws_size,
                              hipStream_t stream) {
  const float* z   = (const float*)d_in[0];
  const float* emb = (const float*)d_in[1];
  float* out = (float*)d_out;
  char* ws = (char*)d_ws;

  double*   loss_acc = (double*)(ws + WS_LOSS);
  int*      flag_cnt = (int*)(ws + WS_CNT);
  float*    enorm    = (float*)(ws + WS_ENORM);
  _Float16* eh       = (_Float16*)(ws + WS_EH);
  _Float16* el       = (_Float16*)(ws + WS_EL);
  int*      flags    = (int*)(ws + WS_FLAGS);

  float* loss_out = out + ZQ_SIZE;
  float* out_idx  = out + ZQ_SIZE + 1;

  hipMemsetAsync(d_ws, 0, 16, stream);
  vq_prep<<<KCODES * CH / 256, 256, 0, stream>>>(emb, eh, el);
  vq_enorm<<<KCODES / 256, 256, 0, stream>>>(emb, enorm);
  vq_main<<<NPTS / 64, 256, 0, stream>>>(z, eh, el, enorm, emb, out_idx, out,
                                         loss_acc, flag_cnt, flags);
  vq_recheck<<<512, 256, 0, stream>>>(z, emb, enorm, flag_cnt, flags, out_idx,
                                      out, loss_acc, loss_out);
}

// Round 11
// 806.660 us; speedup vs baseline: 5.7434x; 1.0020x over previous
//
#include <hip/hip_runtime.h>

#define SPATIAL 32768
#define BATCH   4
#define CH      256
#define KCODES  1024
#define NPTS    (BATCH*SPATIAL)          // 131072
#define ZQ_SIZE (BATCH*CH*SPATIAL)       // 33554432

// workspace layout (bytes)
#define WS_LOSS  0                        // double
#define WS_CNT   8                        // int
#define WS_ENORM 16                       // float[1024]
#define WS_EH    4352                     // _Float16[1024*256] row-major
#define WS_EL    (WS_EH + KCODES*CH*2)
#define WS_FLAGS (WS_EL + KCODES*CH*2)    // int[NPTS]

#define MARG 1.5e-4f  // covers split err + MFMA-vs-chain diff + 2 ulp(512)

typedef _Float16 f16x8 __attribute__((ext_vector_type(8)));
typedef float    f32x4 __attribute__((ext_vector_type(4)));

// split e*1024 into f16 hi/lo, row-major
__global__ __launch_bounds__(256) void vq_prep(const float* __restrict__ emb,
                                               _Float16* __restrict__ eh,
                                               _Float16* __restrict__ el) {
  int i = blockIdx.x * 256 + threadIdx.x;
  float es = emb[i] * 1024.0f;
  _Float16 h = (_Float16)es;
  eh[i] = h;
  el[i] = (_Float16)(es - (float)h);
}

__global__ __launch_bounds__(256) void vq_enorm(const float* __restrict__ emb,
                                                float* __restrict__ enorm) {
  int k = blockIdx.x * 256 + threadIdx.x;
  const float* e = emb + (size_t)k * CH;
  double s = 0.0;
#pragma unroll 8
  for (int c = 0; c < CH; ++c) s = fma((double)e[c], (double)e[c], s);
  enorm[k] = (float)s;
}

// 2048 blocks x 256 thr; block = 64 points x all 1024 codes, f16-split MFMA.
// Fold on p' = en - 2g (zn dropped: per-point constant, argmin/gap-invariant;
// zn re-added only in f64 loss). Lean registers: no znr/en_reg, f32 staging
// partials -> arch VGPR + AGPR stays under the 256 1-wave cliff (r10 lesson).
__global__ __launch_bounds__(256) void vq_main(
    const float* __restrict__ z, const _Float16* __restrict__ eh_g,
    const _Float16* __restrict__ el_g, const float* __restrict__ enorm,
    const float* __restrict__ emb, float* __restrict__ out_idx,
    float* __restrict__ zq, double* __restrict__ loss_acc,
    int* __restrict__ flag_cnt, int* __restrict__ flags) {
  __shared__ __align__(16) char smem[65536];
  f16x8 (*zfrag)[64] = reinterpret_cast<f16x8(*)[64]>(smem);  // 64 KB
  float (*rows)[256] = reinterpret_cast<float(*)[256]>(smem); // union, post-K
  __shared__ float znp[4][64];
  __shared__ float znb[64];
  __shared__ float rm1s[4][64];
  __shared__ float rm2s[4][64];
  __shared__ int   ri1s[4][64];
  __shared__ int   idx_sh[64];

  int tid = threadIdx.x;
  int w = tid >> 6;
  int lane = tid & 63;
  int n0 = blockIdx.x * 64;
  int b = n0 / SPATIAL, s0 = n0 % SPATIAL;
  const float* zb = z + (size_t)b * CH * SPATIAL + s0;

  // stage z as f16 hi/lo in fragment order; f32 zn partials (loss-only)
  {
    int pt = lane, m = pt >> 4, lr0 = pt & 15;
    const float* zcol = zb + pt;
    float zacc = 0.f;
#pragma unroll
    for (int oct = 0; oct < 8; ++oct) {
      int c0 = w * 64 + oct * 8;
      int cc = c0 >> 5, hq0 = (c0 >> 3) & 3;
      f16x8 h8, l8;
#pragma unroll
      for (int i = 0; i < 8; ++i) {
        float v = zcol[(size_t)(c0 + i) * SPATIAL];
        zacc = fmaf(v, v, zacc);
        _Float16 hh = (_Float16)v;
        h8[i] = hh;
        l8[i] = (_Float16)(v - (float)hh);
      }
      zfrag[m * 8 + cc][hq0 * 16 + lr0] = h8;
      zfrag[32 + m * 8 + cc][hq0 * 16 + lr0] = l8;
    }
    znp[w][pt] = zacc;
  }
  __syncthreads();
  if (tid < 64)
    znb[tid] = znp[0][tid] + znp[1][tid] + znp[2][tid] + znp[3][tid];
  __syncthreads();

  int hq = lane >> 4;
  int lr = lane & 15;

  float rm1[16], rm2[16];
  int   ri1[16];
#pragma unroll
  for (int q = 0; q < 16; ++q) { rm1[q] = 1e30f; rm2[q] = 1e30f; ri1[q] = 0; }

  const _Float16* ehb = eh_g + (size_t)(w * 32 + lr) * CH;
  const _Float16* elb = el_g + (size_t)(w * 32 + lr) * CH;

  for (int kt = 0; kt < 8; ++kt) {
    size_t ko = (size_t)kt * 128 * CH;
    f32x4 acc[4][2];
#pragma unroll
    for (int m = 0; m < 4; ++m)
#pragma unroll
      for (int n = 0; n < 2; ++n) acc[m][n] = (f32x4){0.f, 0.f, 0.f, 0.f};

#pragma unroll
    for (int cc = 0; cc < 8; ++cc) {
      int ca = cc * 32 + hq * 8;
      f16x8 bh0 = *(const f16x8*)&ehb[ko + ca];
      f16x8 bh1 = *(const f16x8*)&ehb[ko + (size_t)16 * CH + ca];
      f16x8 bl0 = *(const f16x8*)&elb[ko + ca];
      f16x8 bl1 = *(const f16x8*)&elb[ko + (size_t)16 * CH + ca];
#pragma unroll
      for (int m = 0; m < 4; ++m) {
        f16x8 ah = zfrag[m * 8 + cc][lane];
        f16x8 al = zfrag[32 + m * 8 + cc][lane];
        acc[m][0] = __builtin_amdgcn_mfma_f32_16x16x32_f16(ah, bh0, acc[m][0], 0, 0, 0);
        acc[m][0] = __builtin_amdgcn_mfma_f32_16x16x32_f16(al, bh0, acc[m][0], 0, 0, 0);
        acc[m][0] = __builtin_amdgcn_mfma_f32_16x16x32_f16(ah, bl0, acc[m][0], 0, 0, 0);
        acc[m][1] = __builtin_amdgcn_mfma_f32_16x16x32_f16(ah, bh1, acc[m][1], 0, 0, 0);
        acc[m][1] = __builtin_amdgcn_mfma_f32_16x16x32_f16(al, bh1, acc[m][1], 0, 0, 0);
        acc[m][1] = __builtin_amdgcn_mfma_f32_16x16x32_f16(ah, bl1, acc[m][1], 0, 0, 0);
      }
    }

    // fold into per-thread top-2 on p' = en - 2g (no zn)
    float enA = enorm[kt * 128 + w * 32 + lr];
    float enB = enorm[kt * 128 + w * 32 + 16 + lr];
    int c0i = kt * 128 + w * 32 + lr;
#pragma unroll
    for (int m = 0; m < 4; ++m) {
#pragma unroll
      for (int r = 0; r < 4; ++r) {
        int q = m * 4 + r;
        float p0 = fmaf(acc[m][0][r], -0x1p-9f, enA);
        if (p0 < rm1[q]) { rm2[q] = rm1[q]; rm1[q] = p0; ri1[q] = c0i; }
        else             { rm2[q] = fminf(rm2[q], p0); }
        float p1 = fmaf(acc[m][1][r], -0x1p-9f, enB);
        if (p1 < rm1[q]) { rm2[q] = rm1[q]; rm1[q] = p1; ri1[q] = c0i + 16; }
        else             { rm2[q] = fminf(rm2[q], p1); }
      }
    }
  }

  // one butterfly per row across the 16 lr-lanes (true top-2 merge)
#pragma unroll
  for (int m = 0; m < 4; ++m) {
#pragma unroll
    for (int r = 0; r < 4; ++r) {
      int q = m * 4 + r;
      float m1 = rm1[q], m2 = rm2[q];
      int i1 = ri1[q];
#pragma unroll
      for (int msk = 1; msk <= 8; msk <<= 1) {
        float om1 = __shfl_xor(m1, msk);
        float om2 = __shfl_xor(m2, msk);
        int   oi1 = __shfl_xor(i1, msk);
        if (om1 < m1 || (om1 == m1 && oi1 < i1)) {
          m2 = fminf(m1, om2); m1 = om1; i1 = oi1;
        } else {
          m2 = fminf(m2, om1);
        }
      }
      if (lr == 0) {
        int pt = m * 16 + hq * 4 + r;
        rm1s[w][pt] = m1; rm2s[w][pt] = m2; ri1s[w][pt] = i1;
      }
    }
  }
  __syncthreads();

  if (tid < 64) {
    float m1 = rm1s[0][tid], m2 = rm2s[0][tid];
    int i1 = ri1s[0][tid];
#pragma unroll
    for (int pq = 1; pq < 4; ++pq) {
      float a1 = rm1s[pq][tid], a2 = rm2s[pq][tid];
      int ai = ri1s[pq][tid];
      if (a1 < m1 || (a1 == m1 && ai < i1)) {
        m2 = fminf(m1, a2); m1 = a1; i1 = ai;
      } else {
        m2 = fminf(m2, a1);
      }
    }
    int n = n0 + tid;
    out_idx[n] = (float)i1;
    idx_sh[tid] = i1;
    if (m2 - m1 <= MARG) {
      int p = atomicAdd(flag_cnt, 1);
      if (p < NPTS) flags[p] = n;
    }
    double dv = (double)znb[tid] + (double)m1;   // full ||z-e||^2
#pragma unroll
    for (int msk = 1; msk < 64; msk <<= 1) dv += __shfl_xor(dv, msk);
    if (tid == 0) atomicAdd(loss_acc, dv);
  }
  __syncthreads();

  // fused scatter: gather emb rows once into XOR-swizzled LDS (zfrag space),
  // write z_q transposed coalesced
  for (int r = w; r < 64; r += 4) {
    const float* er = emb + (size_t)idx_sh[r] * CH;
    int sw = r & 31;
#pragma unroll
    for (int i = 0; i < 4; ++i) {
      int c = lane + 64 * i;
      rows[r][c ^ sw] = er[c];
    }
  }
  __syncthreads();
  for (int it = 0; it < 64; ++it) {
    int c = w * 64 + it;
    float v = rows[lane][c ^ (lane & 31)];
    zq[((size_t)(b * CH + c)) * SPATIAL + s0 + lane] = v;
  }
}

// exact numpy-fp32-chain re-decision for flagged points; repairs z_q rows
// whose index changed; finalizes loss.
__global__ __launch_bounds__(256) void vq_recheck(
    const float* __restrict__ z, const float* __restrict__ emb,
    const float* __restrict__ enorm, const int* __restrict__ flag_cnt,
    const int* __restrict__ flags, float* __restrict__ out_idx,
    float* __restrict__ zq, const double* __restrict__ loss_acc,
    float* __restrict__ loss_out) {
  if (blockIdx.x == 0 && threadIdx.x == 0)
    loss_out[0] = (float)(loss_acc[0] * 1.25 / (double)ZQ_SIZE);
  __shared__ float zs[4][CH];
  __shared__ float znf[4];
  __shared__ float bm[256];
  __shared__ int   bi[256];
  __shared__ int   s_n[4], s_old[4], s_new[4];
  int cnt = *flag_cnt; if (cnt > NPTS) cnt = NPTS;
  int t = threadIdx.x;
  for (int base = blockIdx.x * 4; base < cnt; base += gridDim.x * 4) {
    if (t < 4) {
      int ii = base + t; if (ii >= cnt) ii = cnt - 1;
      int nn = flags[ii];
      s_n[t] = nn;
      s_old[t] = (int)out_idx[nn];
    }
    __syncthreads();
#pragma unroll
    for (int q = 0; q < 4; ++q) {
      int n = s_n[q];
      int b = n / SPATIAL, s = n % SPATIAL;
      zs[q][t] = z[((size_t)b * CH + t) * SPATIAL + s];
    }
    __syncthreads();
    if (t < 4) {
      double sd = 0.0;
      for (int c = 0; c < CH; ++c) sd = fma((double)zs[t][c], (double)zs[t][c], sd);
      znf[t] = (float)sd;
    }
    __syncthreads();
    float best[4] = {1e30f, 1e30f, 1e30f, 1e30f};
    int besti[4] = {0, 0, 0, 0};
    for (int q = 0; q < 4; ++q) {
      int code = t + 256 * q;
      const float* er = emb + (size_t)code * CH;
      float g0 = 0.f, g1 = 0.f, g2 = 0.f, g3 = 0.f;
#pragma unroll 8
      for (int c = 0; c < CH; ++c) {
        float e = er[c];
        g0 = fmaf(zs[0][c], e, g0);
        g1 = fmaf(zs[1][c], e, g1);
        g2 = fmaf(zs[2][c], e, g2);
        g3 = fmaf(zs[3][c], e, g3);
      }
      float en = enorm[code];
      float d0 = (znf[0] + en) - 2.f * g0;
      float d1 = (znf[1] + en) - 2.f * g1;
      float d2 = (znf[2] + en) - 2.f * g2;
      float d3 = (znf[3] + en) - 2.f * g3;
      if (d0 < best[0]) { best[0] = d0; besti[0] = code; }
      if (d1 < best[1]) { best[1] = d1; besti[1] = code; }
      if (d2 < best[2]) { best[2] = d2; besti[2] = code; }
      if (d3 < best[3]) { best[3] = d3; besti[3] = code; }
    }
#pragma unroll
    for (int p = 0; p < 4; ++p) {
      bm[t] = best[p]; bi[t] = besti[p];
      __syncthreads();
      for (int off = 128; off > 0; off >>= 1) {
        if (t < off) {
          float ob = bm[t + off]; int oi = bi[t + off];
          if (ob < bm[t] || (ob == bm[t] && oi < bi[t])) { bm[t] = ob; bi[t] = oi; }
        }
        __syncthreads();
      }
      int ii = base + p;
      if (t == 0) {
        s_new[p] = bi[0];
        if (ii < cnt) out_idx[flags[ii]] = (float)bi[0];
      }
      __syncthreads();
    }
    // repair z_q rows whose index changed (thread t = channel t)
#pragma unroll
    for (int p = 0; p < 4; ++p) {
      int ii = base + p;
      if (ii < cnt && s_new[p] != s_old[p]) {
        int n = s_n[p];
        int b = n / SPATIAL, s = n % SPATIAL;
        zq[((size_t)(b * CH + t)) * SPATIAL + s] = emb[(size_t)s_new[p] * CH + t];
      }
    }
    __syncthreads();
  }
}

extern "C" void kernel_launch(void* const* d_in, const int* in_sizes, int n_in,
                              void* d_out, int out_size, void* d_ws, size_t ws_size,
                              hipStream_t stream) {
  const float* z   = (const float*)d_in[0];
  const float* emb = (const float*)d_in[1];
  float* out = (float*)d_out;
  char* ws = (char*)d_ws;

  double*   loss_acc = (double*)(ws + WS_LOSS);
  int*      flag_cnt = (int*)(ws + WS_CNT);
  float*    enorm    = (float*)(ws + WS_ENORM);
  _Float16* eh       = (_Float16*)(ws + WS_EH);
  _Float16* el       = (_Float16*)(ws + WS_EL);
  int*      flags    = (int*)(ws + WS_FLAGS);

  float* loss_out = out + ZQ_SIZE;
  float* out_idx  = out + ZQ_SIZE + 1;

  hipMemsetAsync(d_ws, 0, 16, stream);
  vq_prep<<<KCODES * CH / 256, 256, 0, stream>>>(emb, eh, el);
  vq_enorm<<<KCODES / 256, 256, 0, stream>>>(emb, enorm);
  vq_main<<<NPTS / 64, 256, 0, stream>>>(z, eh, el, enorm, emb, out_idx, out,
                                         loss_acc, flag_cnt, flags);
  vq_recheck<<<512, 256, 0, stream>>>(z, emb, enorm, flag_cnt, flags, out_idx,
                                      out, loss_acc, loss_out);
}